// Round 9
// baseline (261.482 us; speedup 1.0000x reference)
//
#include <hip/hip_runtime.h>

// N=64, C=128, S=H*W=1024. f32 I/O; bf16 MFMA (16x16x32) internally.
// ws: 8KB stats (4 partials) + kT 16MB (bf16 [n][s][c]) + vN 16MB ([n][c][s]).
// R9: attn j-split-64 — v1 structure/sync/swizzles verbatim, but each block
// handles 64 j-cols: grid (64,16)=1024 blocks, LDS 41.2KB -> 3 blocks/CU
// (launch_bounds(256,3)), per-wave state halved. stats/proj = R8 verbatim.

#define NS 64
#define CD 128
#define SD 1024
#define MEL (CD*SD)
#define SCALE2 0.1275174464f   // (1/sqrt(128)) * log2(e)

typedef __attribute__((ext_vector_type(4))) float floatx4;
typedef __attribute__((ext_vector_type(8))) short short8;
typedef __attribute__((ext_vector_type(4))) short short4v;

typedef __attribute__((address_space(1))) const void global_cvoid;
typedef __attribute__((address_space(3))) void lds_void;

__device__ __forceinline__ void gl16(const void* g, void* l) {
  __builtin_amdgcn_global_load_lds((global_cvoid*)g, (lds_void*)l, 16, 0, 0);
}
__device__ __forceinline__ unsigned short f2bf(float f) {
  union { float f; unsigned int i; } v; v.f = f;
  unsigned int i = v.i;
  return (unsigned short)((i + 0x7fffu + ((i >> 16) & 1u)) >> 16);  // RNE
}
__device__ __forceinline__ unsigned int pkbf(float lo, float hi) {
  unsigned int r;
  asm("v_cvt_pk_bf16_f32 %0, %1, %2" : "=v"(r) : "v"(lo), "v"(hi));  // RNE pack
  return r;
}
__device__ __forceinline__ float fexp2(float x) {   // 2^x
  float r; asm("v_exp_f32 %0, %1" : "=v"(r) : "v"(x)); return r;
}
__device__ __forceinline__ short8 ld8_bf16(const float* __restrict__ p) {
  floatx4 a = *(const floatx4*)p;
  floatx4 b = *(const floatx4*)(p + 4);
  union { unsigned int u[4]; short8 s; } r;
  r.u[0] = pkbf(a[0], a[1]);
  r.u[1] = pkbf(a[2], a[3]);
  r.u[2] = pkbf(b[0], b[1]);
  r.u[3] = pkbf(b[2], b[3]);
  return r.s;
}
__device__ __forceinline__ floatx4 mfma16(short8 a, short8 b, floatx4 c) {
  return __builtin_amdgcn_mfma_f32_16x16x32_bf16(a, b, c, 0, 0, 0);
}

// ---------------- Kernel 1: per-(tensor,sample) sum / sumsq ----------------
// 768 blocks: 4 partials per (t,n) -> exactly 3 blocks/CU, balanced.
__global__ __launch_bounds__(512) void stats_kernel(
    const float* __restrict__ q, const float* __restrict__ k,
    const float* __restrict__ v, float* __restrict__ sums)
{
  int b = blockIdx.x;                 // 0..767
  int tn = b >> 2, part = b & 3;
  int t = tn >> 6;
  const float* x = (t == 0 ? q : (t == 1 ? k : v))
                 + (size_t)(tn & 63) * MEL + part * (MEL / 4);
  float s1 = 0.f, s2 = 0.f;
#pragma unroll
  for (int it = 0; it < 16; ++it) {
    floatx4 u = *(const floatx4*)(x + it * 2048 + threadIdx.x * 4);
#pragma unroll
    for (int j = 0; j < 4; ++j) { float f = u[j]; s1 += f; s2 += f * f; }
  }
#pragma unroll
  for (int off = 32; off; off >>= 1) {
    s1 += __shfl_xor(s1, off, 64);
    s2 += __shfl_xor(s2, off, 64);
  }
  __shared__ float r1[8], r2[8];
  int w = threadIdx.x >> 6;
  if ((threadIdx.x & 63) == 0) { r1[w] = s1; r2[w] = s2; }
  __syncthreads();
  if (threadIdx.x == 0) {
    float a = 0.f, c = 0.f;
#pragma unroll
    for (int i = 0; i < 8; ++i) { a += r1[i]; c += r2[i]; }
    sums[part * 192 + tn] = a;
    sums[768 + part * 192 + tn] = c;
  }
}

__device__ __forceinline__ void ln_coeffs(const float* __restrict__ sums,
                                          int g, float& a_ln, float& b_ln)
{
  float s1 = ((sums[g] + sums[192 + g]) + (sums[384 + g] + sums[576 + g]));
  float s2 = ((sums[768 + g] + sums[960 + g]) + (sums[1152 + g] + sums[1344 + g]));
  float mu  = s1 * (1.f / MEL);
  float var = s2 * (1.f / MEL) - mu * mu;
  float rs  = rsqrtf(var + 1e-5f);
  a_ln = rs; b_ln = -mu * rs;
}

// ---------------- Kernel 2: fused LN + 1x1-conv for K and V ----------------
__global__ __launch_bounds__(512, 4) void proj_kernel(
  const float* __restrict__ k, const float* __restrict__ v,
  const float* __restrict__ l2w, const float* __restrict__ l2b,
  const float* __restrict__ l3w, const float* __restrict__ l3b,
  const float* __restrict__ wk, const float* __restrict__ bk,
  const float* __restrict__ wv, const float* __restrict__ bv,
  const float* __restrict__ sums,
  unsigned short* __restrict__ kT, unsigned short* __restrict__ vN)
{
  int n  = blockIdx.x, t = blockIdx.y, st = blockIdx.z;
  const float* x  = (t == 0 ? k : v) + (size_t)n * MEL;
  const float* lw = (t == 0 ? l2w : l3w);
  const float* lb = (t == 0 ? l2b : l3b);
  const float* W  = (t == 0 ? wk : wv);
  const float* Bs = (t == 0 ? bk : bv);

  float a_ln, b_ln;
  ln_coeffs(sums, (t + 1) * 64 + n, a_ln, b_ln);

  __shared__ __align__(16) unsigned short Xt[128 * 136];  // [s][c], stride 136

  int tid = threadIdx.x;
  int cb = tid & 15, sb = (tid >> 4) & 15, half = tid >> 8;
  int s0 = st * 128;

  unsigned int w32[8][2];
#pragma unroll
  for (int pr = 0; pr < 2; ++pr) {
    int c0 = cb * 8 + half * 4 + pr * 2;
    const float* xp0 = x  + (size_t)c0 * SD + s0 + sb * 8;
    const float* wp0 = lw + (size_t)c0 * SD + s0 + sb * 8;
    const float* bp0 = lb + (size_t)c0 * SD + s0 + sb * 8;
    float xv0[8], xv1[8], wv0[8], wv1[8], bv0[8], bv1[8];
    *(floatx4*)xv0 = *(const floatx4*)xp0;       *(floatx4*)(xv0+4) = *(const floatx4*)(xp0+4);
    *(floatx4*)xv1 = *(const floatx4*)(xp0+SD);  *(floatx4*)(xv1+4) = *(const floatx4*)(xp0+SD+4);
    *(floatx4*)wv0 = *(const floatx4*)wp0;       *(floatx4*)(wv0+4) = *(const floatx4*)(wp0+4);
    *(floatx4*)wv1 = *(const floatx4*)(wp0+SD);  *(floatx4*)(wv1+4) = *(const floatx4*)(wp0+SD+4);
    *(floatx4*)bv0 = *(const floatx4*)bp0;       *(floatx4*)(bv0+4) = *(const floatx4*)(bp0+4);
    *(floatx4*)bv1 = *(const floatx4*)(bp0+SD);  *(floatx4*)(bv1+4) = *(const floatx4*)(bp0+SD+4);
#pragma unroll
    for (int js = 0; js < 8; ++js) {
      float lo = (xv0[js] * a_ln + b_ln) * wv0[js] + bv0[js];
      float hi = (xv1[js] * a_ln + b_ln) * wv1[js] + bv1[js];
      w32[js][pr] = pkbf(lo, hi);
    }
  }
#pragma unroll
  for (int js = 0; js < 8; ++js) {
    unsigned int* d = (unsigned int*)&Xt[(sb * 8 + js) * 136 + cb * 8 + half * 4];
    d[0] = w32[js][0]; d[1] = w32[js][1];
  }
  __syncthreads();

  int lane = tid & 63, w = tid >> 6;
  int quad = lane >> 4, l16 = lane & 15;

  short8 Af[4];
#pragma unroll
  for (int kk = 0; kk < 4; ++kk)
    Af[kk] = ld8_bf16(W + (w * 16 + l16) * CD + kk * 32 + quad * 8);

  floatx4 acc[8];
  floatx4 zz = {0.f, 0.f, 0.f, 0.f};
#pragma unroll
  for (int nb = 0; nb < 8; ++nb) acc[nb] = zz;
#pragma unroll
  for (int kk = 0; kk < 4; ++kk)
#pragma unroll
    for (int nb = 0; nb < 8; ++nb) {
      short8 Bf = *(const short8*)&Xt[(nb * 16 + l16) * 136 + kk * 32 + quad * 8];
      acc[nb] = mfma16(Af[kk], Bf, acc[nb]);
    }

  float bsv[4];
#pragma unroll
  for (int r = 0; r < 4; ++r) bsv[r] = Bs[w * 16 + quad * 4 + r];

  __syncthreads();
  unsigned short* Ot = Xt;             // 128 x 130 ushort
#pragma unroll
  for (int nb = 0; nb < 8; ++nb) {
    if (t == 0) {
      unsigned int* d = (unsigned int*)&Ot[(nb * 16 + l16) * 130 + w * 16 + quad * 4];
      d[0] = pkbf(acc[nb][0] + bsv[0], acc[nb][1] + bsv[1]);
      d[1] = pkbf(acc[nb][2] + bsv[2], acc[nb][3] + bsv[3]);
    } else {
      int sl = nb * 16 + l16;
#pragma unroll
      for (int r = 0; r < 4; ++r)
        Ot[(w * 16 + quad * 4 + r) * 130 + sl] = f2bf(acc[nb][r] + bsv[r]);
    }
  }
  __syncthreads();
  unsigned short* gbase = (t == 0) ? (kT + (size_t)n * MEL + (size_t)s0 * CD)
                                   : (vN + (size_t)n * MEL + s0);
#pragma unroll
  for (int p = 0; p < 4; ++p) {
    int g = p * 512 + tid;
    int row = g >> 4, chunk = g & 15;
    short8 val = *(const short8*)&Ot[row * 130 + chunk * 8];
    if (t == 0)
      *(short8*)(gbase + (size_t)row * CD + chunk * 8) = val;
    else
      *(short8*)(gbase + (size_t)row * SD + chunk * 8) = val;
  }
}

// ------- Kernel 3: fused q-proj + flash attention (no-max softmax) -------
// j-split-64: block = (n, jt) covers j0=jt*64 .. +64. 256 thr / 4 waves.
// LDS: Ks[64][128]@0 (16K), Vs[128][64]@16384 (16K), Ps[64][64]@32768 (8K),
// l_s[64]@40960. Phase-A Xt[64][136] (17.4K) aliases [0,17408).
__global__ __launch_bounds__(256, 3) void attn_kernel(
  const float* __restrict__ qraw, const float* __restrict__ l1w,
  const float* __restrict__ l1b, const float* __restrict__ wq,
  const float* __restrict__ bq,
  const unsigned short* __restrict__ kT, const unsigned short* __restrict__ vN,
  const float* __restrict__ sums, float* __restrict__ out)
{
  int n = blockIdx.x, jt = blockIdx.y;
  int j0 = jt * 64;

  __shared__ __align__(16) char smem[41216];
  unsigned short* Xt = (unsigned short*)smem;
  unsigned short* Ks = (unsigned short*)smem;                  // 16KB
  unsigned short* Vs = (unsigned short*)(smem + 16384);        // 16KB
  unsigned short* Ps = (unsigned short*)(smem + 32768);        // 8KB
  float* l_s = (float*)(smem + 40960);                         // 64 floats

  int tid = threadIdx.x, lane = tid & 63, w = tid >> 6;
  int quad = lane >> 4, l16 = lane & 15;

  float a_ln, b_ln;
  ln_coeffs(sums, n, a_ln, b_ln);
  const float* qb = qraw + (size_t)n * MEL;

  // --- Phase A: LN1(q) -> Xt[j][c] (64 j x 128 c), 4c x 8j register blocks ---
  {
    int cb = tid & 15, sb = (tid >> 4) & 7, half = tid >> 7;   // 16 x 8 x 2
    unsigned int w32[8][2];
#pragma unroll
    for (int pr = 0; pr < 2; ++pr) {
      int c0 = cb * 8 + half * 4 + pr * 2;
      const float* xp0 = qb  + (size_t)c0 * SD + j0 + sb * 8;
      const float* wp0 = l1w + (size_t)c0 * SD + j0 + sb * 8;
      const float* bp0 = l1b + (size_t)c0 * SD + j0 + sb * 8;
      float xv0[8], xv1[8], wv0[8], wv1[8], bv0[8], bv1[8];
      *(floatx4*)xv0 = *(const floatx4*)xp0;       *(floatx4*)(xv0+4) = *(const floatx4*)(xp0+4);
      *(floatx4*)xv1 = *(const floatx4*)(xp0+SD);  *(floatx4*)(xv1+4) = *(const floatx4*)(xp0+SD+4);
      *(floatx4*)wv0 = *(const floatx4*)wp0;       *(floatx4*)(wv0+4) = *(const floatx4*)(wp0+4);
      *(floatx4*)wv1 = *(const floatx4*)(wp0+SD);  *(floatx4*)(wv1+4) = *(const floatx4*)(wp0+SD+4);
      *(floatx4*)bv0 = *(const floatx4*)bp0;       *(floatx4*)(bv0+4) = *(const floatx4*)(bp0+4);
      *(floatx4*)bv1 = *(const floatx4*)(bp0+SD);  *(floatx4*)(bv1+4) = *(const floatx4*)(bp0+SD+4);
#pragma unroll
      for (int js = 0; js < 8; ++js) {
        float lo = (xv0[js] * a_ln + b_ln) * wv0[js] + bv0[js];
        float hi = (xv1[js] * a_ln + b_ln) * wv1[js] + bv1[js];
        w32[js][pr] = pkbf(lo, hi);
      }
    }
#pragma unroll
    for (int js = 0; js < 8; ++js) {
      unsigned int* d = (unsigned int*)&Xt[(sb * 8 + js) * 136 + cb * 8 + half * 4];
      d[0] = w32[js][0]; d[1] = w32[js][1];
    }
  }
  __syncthreads();

  // q-projection: C[c_out 128][j 64] = wq . Xt ; wave w -> c_out rows [w*32,+32)
  floatx4 zz = {0.f, 0.f, 0.f, 0.f};
  {
    short8 Af[2][4];
#pragma unroll
    for (int mi = 0; mi < 2; ++mi)
#pragma unroll
      for (int kk = 0; kk < 4; ++kk)
        Af[mi][kk] = ld8_bf16(wq + ((w * 2 + mi) * 16 + l16) * CD + kk * 32 + quad * 8);
    floatx4 accq[2][4];
#pragma unroll
    for (int mi = 0; mi < 2; ++mi)
#pragma unroll
      for (int nb = 0; nb < 4; ++nb) accq[mi][nb] = zz;
#pragma unroll
    for (int kk = 0; kk < 4; ++kk)
#pragma unroll
      for (int nb = 0; nb < 4; ++nb) {
        short8 Bf = *(const short8*)&Xt[(nb * 16 + l16) * 136 + kk * 32 + quad * 8];
        accq[0][nb] = mfma16(Af[0][kk], Bf, accq[0][nb]);
        accq[1][nb] = mfma16(Af[1][kk], Bf, accq[1][nb]);
      }
    __syncthreads();
    float bqs[2][4];
#pragma unroll
    for (int mi = 0; mi < 2; ++mi)
#pragma unroll
      for (int r = 0; r < 4; ++r) bqs[mi][r] = bq[(w * 2 + mi) * 16 + quad * 4 + r];
#pragma unroll
    for (int mi = 0; mi < 2; ++mi)
#pragma unroll
      for (int nb = 0; nb < 4; ++nb) {
        unsigned int* d = (unsigned int*)&Xt[(nb * 16 + l16) * 136 + (w * 2 + mi) * 16 + quad * 4];
        d[0] = pkbf(accq[mi][nb][0] + bqs[mi][0], accq[mi][nb][1] + bqs[mi][1]);
        d[1] = pkbf(accq[mi][nb][2] + bqs[mi][2], accq[mi][nb][3] + bqs[mi][3]);
      }
  }
  __syncthreads();

  short8 Qf[4];    // B-frags: wave owns j-tile w: j = w*16 + l16
#pragma unroll
  for (int kk = 0; kk < 4; ++kk)
    Qf[kk] = *(const short8*)&Xt[(w * 16 + l16) * 136 + kk * 32 + quad * 8];
  __syncthreads();   // Xt region about to be overwritten by Ks/Vs

  floatx4 Oc[2][4];
#pragma unroll
  for (int mi = 0; mi < 2; ++mi)
#pragma unroll
    for (int nb = 0; nb < 4; ++nb) Oc[mi][nb] = zz;
  float lsum = 0.f;

  const unsigned short* kbase0 = kT + (size_t)n * MEL;
  const unsigned short* vbase0 = vN + (size_t)n * MEL;

  for (int itile = 0; itile < 16; ++itile) {
    int i0 = itile * 64;
    // async stage: Ks[i][c] chunks xor-swizzled by (i&7); Vs[c][i] by (c&7)
    const unsigned short* kbase = kbase0 + (size_t)i0 * CD;
#pragma unroll
    for (int it = 0; it < 4; ++it) {
      int nch = w * 256 + it * 64 + lane;
      int i = nch >> 4, cc = nch & 15;
      int csrc = (cc & 8) | ((cc & 7) ^ (i & 7));
      gl16(kbase + i * CD + csrc * 8, (char*)Ks + (w * 256 + it * 64) * 16);
    }
#pragma unroll
    for (int it = 0; it < 4; ++it) {
      int nch = w * 256 + it * 64 + lane;
      int c = nch >> 3, ci = nch & 7;
      int isrc = ci ^ (c & 7);
      gl16(vbase0 + (size_t)c * SD + i0 + isrc * 8, (char*)Vs + (w * 256 + it * 64) * 16);
    }
    __syncthreads();

    // QK: S[i][j], A = K (m=i), B = Q (n=j = w*16+l16)
    floatx4 Sa[4];
#pragma unroll
    for (int mt = 0; mt < 4; ++mt) Sa[mt] = zz;
    __builtin_amdgcn_s_setprio(1);
#pragma unroll
    for (int kk = 0; kk < 4; ++kk)
#pragma unroll
      for (int mt = 0; mt < 4; ++mt) {
        short8 Kf = *(const short8*)&Ks[(mt * 16 + l16) * 128 + (((kk * 4 + quad) ^ (l16 & 7)) * 8)];
        Sa[mt] = mfma16(Kf, Qf[kk], Sa[mt]);
      }
    __builtin_amdgcn_s_setprio(0);

    // no-max softmax: p = exp2(S*scale*log2e); accumulate l; Ps[j][i] writes
    {
      int jrow = w * 16 + l16;
      int rowbase = jrow * 64;
      int sub = (quad & 1) * 4;
#pragma unroll
      for (int mt = 0; mt < 4; ++mt) {
        float p0 = fexp2(Sa[mt][0] * SCALE2);
        float p1 = fexp2(Sa[mt][1] * SCALE2);
        float p2 = fexp2(Sa[mt][2] * SCALE2);
        float p3 = fexp2(Sa[mt][3] * SCALE2);
        lsum += (p0 + p1) + (p2 + p3);
        int ci = mt * 2 + (quad >> 1);
        int cis = ci ^ (l16 & 7);
        unsigned int* d = (unsigned int*)&Ps[rowbase + cis * 8 + sub];
        d[0] = pkbf(p0, p1);
        d[1] = pkbf(p2, p3);
      }
    }
    __syncthreads();

    // PV: O[c][j] += V . P   (A = V m=c rows (w*2+mi)*16, B = P n=j)
#pragma unroll
    for (int kk = 0; kk < 2; ++kk) {
      short8 Vf[2];
#pragma unroll
      for (int mi = 0; mi < 2; ++mi) {
        int c = (w * 2 + mi) * 16 + l16;
        Vf[mi] = *(const short8*)&Vs[c * 64 + (((kk * 4 + quad) ^ (l16 & 7)) * 8)];
      }
      __builtin_amdgcn_s_setprio(1);
#pragma unroll
      for (int nb = 0; nb < 4; ++nb) {
        short8 Pf = *(const short8*)&Ps[(nb * 16 + l16) * 64 + (((kk * 4 + quad) ^ (l16 & 7)) * 8)];
        Oc[0][nb] = mfma16(Vf[0], Pf, Oc[0][nb]);
        Oc[1][nb] = mfma16(Vf[1], Pf, Oc[1][nb]);
      }
      __builtin_amdgcn_s_setprio(0);
    }
    __syncthreads();
  }

  // softmax denominators: lane's lsum covers quad's i-slice for j=w*16+l16;
  // reduce across quads (lanes l16, +16, +32, +48)
  lsum += __shfl_xor(lsum, 16, 64);
  lsum += __shfl_xor(lsum, 32, 64);
  if (lane < 16) l_s[w * 16 + l16] = lsum;
  __syncthreads();

  // epilogue: out[c][j] = O/l + LN1(query)[c][j]
  float linv[4];
#pragma unroll
  for (int nb = 0; nb < 4; ++nb) linv[nb] = 1.f / l_s[nb * 16 + l16];
#pragma unroll
  for (int mi = 0; mi < 2; ++mi) {
#pragma unroll
    for (int r = 0; r < 4; ++r) {
      int c = (w * 2 + mi) * 16 + quad * 4 + r;
      const float* qp = qb  + (size_t)c * SD + j0;
      const float* wp = l1w + (size_t)c * SD + j0;
      const float* bp = l1b + (size_t)c * SD + j0;
      float* op = out + (size_t)n * MEL + (size_t)c * SD + j0;
#pragma unroll
      for (int nb = 0; nb < 4; ++nb) {
        int j = nb * 16 + l16;
        float qn = (qp[j] * a_ln + b_ln) * wp[j] + bp[j];
        op[j] = Oc[mi][nb][r] * linv[nb] + qn;
      }
    }
  }
}

// ---------------- host launch ----------------
extern "C" void kernel_launch(void* const* d_in, const int* in_sizes, int n_in,
                              void* d_out, int out_size, void* d_ws, size_t ws_size,
                              hipStream_t stream)
{
  const float* q   = (const float*)d_in[0];
  const float* k   = (const float*)d_in[1];
  const float* v   = (const float*)d_in[2];
  const float* l1w = (const float*)d_in[3];
  const float* l1b = (const float*)d_in[4];
  const float* l2w = (const float*)d_in[5];
  const float* l2b = (const float*)d_in[6];
  const float* l3w = (const float*)d_in[7];
  const float* l3b = (const float*)d_in[8];
  const float* wq  = (const float*)d_in[9];
  const float* bq  = (const float*)d_in[10];
  const float* wk  = (const float*)d_in[11];
  const float* bk  = (const float*)d_in[12];
  const float* wv  = (const float*)d_in[13];
  const float* bv  = (const float*)d_in[14];

  char* ws = (char*)d_ws;
  float* sums = (float*)ws;                          // [1536] partials (6KB)
  unsigned short* kT = (unsigned short*)(ws + 8192); // [64][1024][128] bf16
  unsigned short* vN = kT + (size_t)NS * MEL;        // [64][128][1024] bf16

  stats_kernel<<<768, 512, 0, stream>>>(q, k, v, sums);
  proj_kernel<<<dim3(64, 2, 8), 512, 0, stream>>>(k, v, l2w, l2b, l3w, l3b,
      wk, bk, wv, bv, sums, kT, vN);
  attn_kernel<<<dim3(64, 16), 256, 0, stream>>>(q, l1w, l1b, wq, bq, kT, vN,
      sums, (float*)d_out);
}

// Round 10
// 248.959 us; speedup vs baseline: 1.0503x; 1.0503x over previous
//
#include <hip/hip_runtime.h>

// N=64, C=128, S=H*W=1024. f32 I/O; bf16 MFMA (16x16x32) internally.
// ws: 8KB stats (4 partials) + kT 16MB (bf16 [n][s][c]) + vN 16MB ([n][c][s]).
// R10: attn = v1 Ps-dataflow + double-buffered K/V + counted vmcnt(8) with
// raw lgkmcnt-only barriers mid-tile (prefetch survives the whole tile).
// LDS 81920B x 2 blocks/CU = exactly 160KiB: Ks0/Vs0/Ks1/Vs1 64K + Ps 16K;
// Xt aliases Ks1/Vs1 (prologue), l_s aliases Ks0 (epilogue). Tile-0 staged
// under phase A. stats/proj = R8 verbatim (best passing, 249.4us).

#define NS 64
#define CD 128
#define SD 1024
#define MEL (CD*SD)
#define SCALE2 0.1275174464f   // (1/sqrt(128)) * log2(e)

typedef __attribute__((ext_vector_type(4))) float floatx4;
typedef __attribute__((ext_vector_type(8))) short short8;
typedef __attribute__((ext_vector_type(4))) short short4v;

typedef __attribute__((address_space(1))) const void global_cvoid;
typedef __attribute__((address_space(3))) void lds_void;

__device__ __forceinline__ void gl16(const void* g, void* l) {
  __builtin_amdgcn_global_load_lds((global_cvoid*)g, (lds_void*)l, 16, 0, 0);
}
__device__ __forceinline__ unsigned short f2bf(float f) {
  union { float f; unsigned int i; } v; v.f = f;
  unsigned int i = v.i;
  return (unsigned short)((i + 0x7fffu + ((i >> 16) & 1u)) >> 16);  // RNE
}
__device__ __forceinline__ unsigned int pkbf(float lo, float hi) {
  unsigned int r;
  asm("v_cvt_pk_bf16_f32 %0, %1, %2" : "=v"(r) : "v"(lo), "v"(hi));  // RNE pack
  return r;
}
__device__ __forceinline__ float fexp2(float x) {   // 2^x
  float r; asm("v_exp_f32 %0, %1" : "=v"(r) : "v"(x)); return r;
}
__device__ __forceinline__ short8 ld8_bf16(const float* __restrict__ p) {
  floatx4 a = *(const floatx4*)p;
  floatx4 b = *(const floatx4*)(p + 4);
  union { unsigned int u[4]; short8 s; } r;
  r.u[0] = pkbf(a[0], a[1]);
  r.u[1] = pkbf(a[2], a[3]);
  r.u[2] = pkbf(b[0], b[1]);
  r.u[3] = pkbf(b[2], b[3]);
  return r.s;
}
__device__ __forceinline__ floatx4 mfma16(short8 a, short8 b, floatx4 c) {
  return __builtin_amdgcn_mfma_f32_16x16x32_bf16(a, b, c, 0, 0, 0);
}

// ---------------- Kernel 1: per-(tensor,sample) sum / sumsq ----------------
// 768 blocks: 4 partials per (t,n) -> exactly 3 blocks/CU, balanced.
__global__ __launch_bounds__(512) void stats_kernel(
    const float* __restrict__ q, const float* __restrict__ k,
    const float* __restrict__ v, float* __restrict__ sums)
{
  int b = blockIdx.x;                 // 0..767
  int tn = b >> 2, part = b & 3;
  int t = tn >> 6;
  const float* x = (t == 0 ? q : (t == 1 ? k : v))
                 + (size_t)(tn & 63) * MEL + part * (MEL / 4);
  float s1 = 0.f, s2 = 0.f;
#pragma unroll
  for (int it = 0; it < 16; ++it) {
    floatx4 u = *(const floatx4*)(x + it * 2048 + threadIdx.x * 4);
#pragma unroll
    for (int j = 0; j < 4; ++j) { float f = u[j]; s1 += f; s2 += f * f; }
  }
#pragma unroll
  for (int off = 32; off; off >>= 1) {
    s1 += __shfl_xor(s1, off, 64);
    s2 += __shfl_xor(s2, off, 64);
  }
  __shared__ float r1[8], r2[8];
  int w = threadIdx.x >> 6;
  if ((threadIdx.x & 63) == 0) { r1[w] = s1; r2[w] = s2; }
  __syncthreads();
  if (threadIdx.x == 0) {
    float a = 0.f, c = 0.f;
#pragma unroll
    for (int i = 0; i < 8; ++i) { a += r1[i]; c += r2[i]; }
    sums[part * 192 + tn] = a;
    sums[768 + part * 192 + tn] = c;
  }
}

__device__ __forceinline__ void ln_coeffs(const float* __restrict__ sums,
                                          int g, float& a_ln, float& b_ln)
{
  float s1 = ((sums[g] + sums[192 + g]) + (sums[384 + g] + sums[576 + g]));
  float s2 = ((sums[768 + g] + sums[960 + g]) + (sums[1152 + g] + sums[1344 + g]));
  float mu  = s1 * (1.f / MEL);
  float var = s2 * (1.f / MEL) - mu * mu;
  float rs  = rsqrtf(var + 1e-5f);
  a_ln = rs; b_ln = -mu * rs;
}

// ---------------- Kernel 2: fused LN + 1x1-conv for K and V ----------------
__global__ __launch_bounds__(512, 4) void proj_kernel(
  const float* __restrict__ k, const float* __restrict__ v,
  const float* __restrict__ l2w, const float* __restrict__ l2b,
  const float* __restrict__ l3w, const float* __restrict__ l3b,
  const float* __restrict__ wk, const float* __restrict__ bk,
  const float* __restrict__ wv, const float* __restrict__ bv,
  const float* __restrict__ sums,
  unsigned short* __restrict__ kT, unsigned short* __restrict__ vN)
{
  int n  = blockIdx.x, t = blockIdx.y, st = blockIdx.z;
  const float* x  = (t == 0 ? k : v) + (size_t)n * MEL;
  const float* lw = (t == 0 ? l2w : l3w);
  const float* lb = (t == 0 ? l2b : l3b);
  const float* W  = (t == 0 ? wk : wv);
  const float* Bs = (t == 0 ? bk : bv);

  float a_ln, b_ln;
  ln_coeffs(sums, (t + 1) * 64 + n, a_ln, b_ln);

  __shared__ __align__(16) unsigned short Xt[128 * 136];  // [s][c], stride 136

  int tid = threadIdx.x;
  int cb = tid & 15, sb = (tid >> 4) & 15, half = tid >> 8;
  int s0 = st * 128;

  unsigned int w32[8][2];
#pragma unroll
  for (int pr = 0; pr < 2; ++pr) {
    int c0 = cb * 8 + half * 4 + pr * 2;
    const float* xp0 = x  + (size_t)c0 * SD + s0 + sb * 8;
    const float* wp0 = lw + (size_t)c0 * SD + s0 + sb * 8;
    const float* bp0 = lb + (size_t)c0 * SD + s0 + sb * 8;
    float xv0[8], xv1[8], wv0[8], wv1[8], bv0[8], bv1[8];
    *(floatx4*)xv0 = *(const floatx4*)xp0;       *(floatx4*)(xv0+4) = *(const floatx4*)(xp0+4);
    *(floatx4*)xv1 = *(const floatx4*)(xp0+SD);  *(floatx4*)(xv1+4) = *(const floatx4*)(xp0+SD+4);
    *(floatx4*)wv0 = *(const floatx4*)wp0;       *(floatx4*)(wv0+4) = *(const floatx4*)(wp0+4);
    *(floatx4*)wv1 = *(const floatx4*)(wp0+SD);  *(floatx4*)(wv1+4) = *(const floatx4*)(wp0+SD+4);
    *(floatx4*)bv0 = *(const floatx4*)bp0;       *(floatx4*)(bv0+4) = *(const floatx4*)(bp0+4);
    *(floatx4*)bv1 = *(const floatx4*)(bp0+SD);  *(floatx4*)(bv1+4) = *(const floatx4*)(bp0+SD+4);
#pragma unroll
    for (int js = 0; js < 8; ++js) {
      float lo = (xv0[js] * a_ln + b_ln) * wv0[js] + bv0[js];
      float hi = (xv1[js] * a_ln + b_ln) * wv1[js] + bv1[js];
      w32[js][pr] = pkbf(lo, hi);
    }
  }
#pragma unroll
  for (int js = 0; js < 8; ++js) {
    unsigned int* d = (unsigned int*)&Xt[(sb * 8 + js) * 136 + cb * 8 + half * 4];
    d[0] = w32[js][0]; d[1] = w32[js][1];
  }
  __syncthreads();

  int lane = tid & 63, w = tid >> 6;
  int quad = lane >> 4, l16 = lane & 15;

  short8 Af[4];
#pragma unroll
  for (int kk = 0; kk < 4; ++kk)
    Af[kk] = ld8_bf16(W + (w * 16 + l16) * CD + kk * 32 + quad * 8);

  floatx4 acc[8];
  floatx4 zz = {0.f, 0.f, 0.f, 0.f};
#pragma unroll
  for (int nb = 0; nb < 8; ++nb) acc[nb] = zz;
#pragma unroll
  for (int kk = 0; kk < 4; ++kk)
#pragma unroll
    for (int nb = 0; nb < 8; ++nb) {
      short8 Bf = *(const short8*)&Xt[(nb * 16 + l16) * 136 + kk * 32 + quad * 8];
      acc[nb] = mfma16(Af[kk], Bf, acc[nb]);
    }

  float bsv[4];
#pragma unroll
  for (int r = 0; r < 4; ++r) bsv[r] = Bs[w * 16 + quad * 4 + r];

  __syncthreads();
  unsigned short* Ot = Xt;             // 128 x 130 ushort
#pragma unroll
  for (int nb = 0; nb < 8; ++nb) {
    if (t == 0) {
      unsigned int* d = (unsigned int*)&Ot[(nb * 16 + l16) * 130 + w * 16 + quad * 4];
      d[0] = pkbf(acc[nb][0] + bsv[0], acc[nb][1] + bsv[1]);
      d[1] = pkbf(acc[nb][2] + bsv[2], acc[nb][3] + bsv[3]);
    } else {
      int sl = nb * 16 + l16;
#pragma unroll
      for (int r = 0; r < 4; ++r)
        Ot[(w * 16 + quad * 4 + r) * 130 + sl] = f2bf(acc[nb][r] + bsv[r]);
    }
  }
  __syncthreads();
  unsigned short* gbase = (t == 0) ? (kT + (size_t)n * MEL + (size_t)s0 * CD)
                                   : (vN + (size_t)n * MEL + s0);
#pragma unroll
  for (int p = 0; p < 4; ++p) {
    int g = p * 512 + tid;
    int row = g >> 4, chunk = g & 15;
    short8 val = *(const short8*)&Ot[row * 130 + chunk * 8];
    if (t == 0)
      *(short8*)(gbase + (size_t)row * CD + chunk * 8) = val;
    else
      *(short8*)(gbase + (size_t)row * SD + chunk * 8) = val;
  }
}

// ------- Kernel 3: fused q-proj + flash attention (no-max softmax) -------
// LDS 81920B: Ks0@0, Vs0@16K, Ks1@32K, Vs1@48K, Ps@64K..80K.
// Xt[128][136] (34816B) aliases [32768,67584) -- Ks1/Vs1(+2K Ps), dead in
// prologue (tile0 staged into Ks0/Vs0 concurrently). l_s aliases smem[0,512)
// after the last tile. Per tile: counted vmcnt(8) + raw barriers (no vmcnt
// drain mid-loop) so stage(i+1) stays in flight through tile i's compute.
__device__ __forceinline__ void stage_tile(
    const unsigned short* __restrict__ kbase0,
    const unsigned short* __restrict__ vbase0,
    char* smem, int ti, int buf, int w, int lane)
{
  const unsigned short* kb = kbase0 + (size_t)ti * 64 * CD;
  char* KD = smem + buf * 32768;
  char* VD = smem + buf * 32768 + 16384;
#pragma unroll
  for (int it = 0; it < 4; ++it) {   // Ks[i][c], chunk-xor by (i&7)
    int nch = w * 256 + it * 64 + lane;
    int i = nch >> 4, cc = nch & 15;
    int csrc = (cc & 8) | ((cc & 7) ^ (i & 7));
    gl16(kb + i * CD + csrc * 8, KD + (w * 256 + it * 64) * 16);
  }
#pragma unroll
  for (int it = 0; it < 4; ++it) {   // Vs[c][i], chunk-xor by (c&7)
    int nch = w * 256 + it * 64 + lane;
    int c = nch >> 3, ci = nch & 7;
    int isrc = ci ^ (c & 7);
    gl16(vbase0 + (size_t)c * SD + ti * 64 + isrc * 8, VD + (w * 256 + it * 64) * 16);
  }
}

__global__ __launch_bounds__(256, 2) void attn_kernel(
  const float* __restrict__ qraw, const float* __restrict__ l1w,
  const float* __restrict__ l1b, const float* __restrict__ wq,
  const float* __restrict__ bq,
  const unsigned short* __restrict__ kT, const unsigned short* __restrict__ vN,
  const float* __restrict__ sums, float* __restrict__ out)
{
  int n = blockIdx.x, jt = blockIdx.y;
  int j0 = jt * 128;

  __shared__ __align__(16) char smem[81920];
  unsigned short* Xt = (unsigned short*)(smem + 32768);
  unsigned short* Ps = (unsigned short*)(smem + 65536);        // 16KB
  float* l_s = (float*)smem;                                   // epilogue alias

  int tid = threadIdx.x, lane = tid & 63, w = tid >> 6;
  int quad = lane >> 4, l16 = lane & 15;

  const unsigned short* kbase0 = kT + (size_t)n * MEL;
  const unsigned short* vbase0 = vN + (size_t)n * MEL;

  // prefetch tile 0 into Ks0/Vs0 [0,32K) -- latency hidden under phase A
  stage_tile(kbase0, vbase0, smem, 0, 0, w, lane);

  float a_ln, b_ln;
  ln_coeffs(sums, n, a_ln, b_ln);
  const float* qb = qraw + (size_t)n * MEL;

  // --- Phase A: LN1(q) -> Xt[j][c] via 8x8 register-transpose blocks ---
  {
    int cb = tid & 15, sb = tid >> 4;       // 16 x 16
    unsigned int w32[8][4];
#pragma unroll
    for (int pr = 0; pr < 4; ++pr) {
      int c0 = cb * 8 + pr * 2;
      const float* xp0 = qb  + (size_t)c0 * SD + j0 + sb * 8;
      const float* wp0 = l1w + (size_t)c0 * SD + j0 + sb * 8;
      const float* bp0 = l1b + (size_t)c0 * SD + j0 + sb * 8;
      float xv0[8], xv1[8], wv0[8], wv1[8], bv0[8], bv1[8];
      *(floatx4*)xv0 = *(const floatx4*)xp0;       *(floatx4*)(xv0+4) = *(const floatx4*)(xp0+4);
      *(floatx4*)xv1 = *(const floatx4*)(xp0+SD);  *(floatx4*)(xv1+4) = *(const floatx4*)(xp0+SD+4);
      *(floatx4*)wv0 = *(const floatx4*)wp0;       *(floatx4*)(wv0+4) = *(const floatx4*)(wp0+4);
      *(floatx4*)wv1 = *(const floatx4*)(wp0+SD);  *(floatx4*)(wv1+4) = *(const floatx4*)(wp0+SD+4);
      *(floatx4*)bv0 = *(const floatx4*)bp0;       *(floatx4*)(bv0+4) = *(const floatx4*)(bp0+4);
      *(floatx4*)bv1 = *(const floatx4*)(bp0+SD);  *(floatx4*)(bv1+4) = *(const floatx4*)(bp0+SD+4);
#pragma unroll
      for (int js = 0; js < 8; ++js) {
        float lo = (xv0[js] * a_ln + b_ln) * wv0[js] + bv0[js];
        float hi = (xv1[js] * a_ln + b_ln) * wv1[js] + bv1[js];
        w32[js][pr] = pkbf(lo, hi);
      }
    }
#pragma unroll
    for (int js = 0; js < 8; ++js)
      *(floatx4*)&Xt[(sb * 8 + js) * 136 + cb * 8] = *(floatx4*)w32[js];
  }
  __syncthreads();

  // q-projection: C[c_out][j] = wq . Xt
  floatx4 zz = {0.f, 0.f, 0.f, 0.f};
  {
    short8 Af[2][4];
#pragma unroll
    for (int mi = 0; mi < 2; ++mi)
#pragma unroll
      for (int kk = 0; kk < 4; ++kk)
        Af[mi][kk] = ld8_bf16(wq + ((w * 2 + mi) * 16 + l16) * CD + kk * 32 + quad * 8);
    floatx4 accq[2][8];
#pragma unroll
    for (int mi = 0; mi < 2; ++mi)
#pragma unroll
      for (int nb = 0; nb < 8; ++nb) accq[mi][nb] = zz;
#pragma unroll
    for (int kk = 0; kk < 4; ++kk)
#pragma unroll
      for (int nb = 0; nb < 8; ++nb) {
        short8 Bf = *(const short8*)&Xt[(nb * 16 + l16) * 136 + kk * 32 + quad * 8];
        accq[0][nb] = mfma16(Af[0][kk], Bf, accq[0][nb]);
        accq[1][nb] = mfma16(Af[1][kk], Bf, accq[1][nb]);
      }
    __syncthreads();
    float bqs[2][4];
#pragma unroll
    for (int mi = 0; mi < 2; ++mi)
#pragma unroll
      for (int r = 0; r < 4; ++r) bqs[mi][r] = bq[(w * 2 + mi) * 16 + quad * 4 + r];
#pragma unroll
    for (int mi = 0; mi < 2; ++mi)
#pragma unroll
      for (int nb = 0; nb < 8; ++nb) {
        unsigned int* d = (unsigned int*)&Xt[(nb * 16 + l16) * 136 + (w * 2 + mi) * 16 + quad * 4];
        d[0] = pkbf(accq[mi][nb][0] + bqs[mi][0], accq[mi][nb][1] + bqs[mi][1]);
        d[1] = pkbf(accq[mi][nb][2] + bqs[mi][2], accq[mi][nb][3] + bqs[mi][3]);
      }
  }
  __syncthreads();

  short8 Qf[2][4];    // B-frags: n = j = (w*2+nt)*16 + l16
#pragma unroll
  for (int nt = 0; nt < 2; ++nt)
#pragma unroll
    for (int kk = 0; kk < 4; ++kk)
      Qf[nt][kk] = *(const short8*)&Xt[((w * 2 + nt) * 16 + l16) * 136 + kk * 32 + quad * 8];
  __syncthreads();   // Xt dead: Ks1/Vs1 region free for staging from iter 0

  floatx4 Oc[2][8];
#pragma unroll
  for (int mi = 0; mi < 2; ++mi)
#pragma unroll
    for (int nb = 0; nb < 8; ++nb) Oc[mi][nb] = zz;
  float lsum[2] = {0.f, 0.f};

  for (int itile = 0; itile < 16; ++itile) {
    int buf = itile & 1;
    if (itile < 15) {
      stage_tile(kbase0, vbase0, smem, itile + 1, buf ^ 1, w, lane);
      asm volatile("s_waitcnt vmcnt(8)" ::: "memory");  // stage(itile) landed
    } else {
      asm volatile("s_waitcnt vmcnt(0)" ::: "memory");
    }
    __builtin_amdgcn_s_barrier();          // all waves' stage(itile) landed
    __builtin_amdgcn_sched_barrier(0);

    const unsigned short* Ks = (const unsigned short*)(smem + buf * 32768);
    const unsigned short* Vs = (const unsigned short*)(smem + buf * 32768 + 16384);

    // QK: S[i][j], A = K (m=i), B = Q (n=j)
    floatx4 Sa[4][2];
#pragma unroll
    for (int mt = 0; mt < 4; ++mt) { Sa[mt][0] = zz; Sa[mt][1] = zz; }
    __builtin_amdgcn_s_setprio(1);
#pragma unroll
    for (int kk = 0; kk < 4; ++kk)
#pragma unroll
      for (int mt = 0; mt < 4; ++mt) {
        short8 Kf = *(const short8*)&Ks[(mt * 16 + l16) * 128 + (((kk * 4 + quad) ^ (l16 & 7)) * 8)];
        Sa[mt][0] = mfma16(Kf, Qf[0][kk], Sa[mt][0]);
        Sa[mt][1] = mfma16(Kf, Qf[1][kk], Sa[mt][1]);
      }
    __builtin_amdgcn_s_setprio(0);

    // no-max softmax: p = exp2(S*scale*log2e); accumulate l; Ps[j][i] writes
#pragma unroll
    for (int nt = 0; nt < 2; ++nt) {
      int jrow = (w * 2 + nt) * 16 + l16;
      int rowbase = jrow * 64;
      int sub = (quad & 1) * 4;
#pragma unroll
      for (int mt = 0; mt < 4; ++mt) {
        float p0 = fexp2(Sa[mt][nt][0] * SCALE2);
        float p1 = fexp2(Sa[mt][nt][1] * SCALE2);
        float p2 = fexp2(Sa[mt][nt][2] * SCALE2);
        float p3 = fexp2(Sa[mt][nt][3] * SCALE2);
        lsum[nt] += (p0 + p1) + (p2 + p3);
        int ci = mt * 2 + (quad >> 1);
        int cis = ci ^ (l16 & 7);
        unsigned int* d = (unsigned int*)&Ps[rowbase + cis * 8 + sub];
        d[0] = pkbf(p0, p1);
        d[1] = pkbf(p2, p3);
      }
    }
    // Ps visibility barrier WITHOUT vmcnt drain (prefetch stays in flight)
    asm volatile("s_waitcnt lgkmcnt(0)" ::: "memory");
    __builtin_amdgcn_s_barrier();
    __builtin_amdgcn_sched_barrier(0);

    // PV: O[c][j] += V . P   (A = V m=c, B = P n=j)
#pragma unroll
    for (int kk = 0; kk < 2; ++kk) {
      short8 Vf[2];
#pragma unroll
      for (int mi = 0; mi < 2; ++mi) {
        int c = (w * 2 + mi) * 16 + l16;
        Vf[mi] = *(const short8*)&Vs[c * 64 + (((kk * 4 + quad) ^ (l16 & 7)) * 8)];
      }
      __builtin_amdgcn_s_setprio(1);
#pragma unroll
      for (int nb = 0; nb < 8; ++nb) {
        short8 Pf = *(const short8*)&Ps[(nb * 16 + l16) * 64 + (((kk * 4 + quad) ^ (l16 & 7)) * 8)];
        Oc[0][nb] = mfma16(Vf[0], Pf, Oc[0][nb]);
        Oc[1][nb] = mfma16(Vf[1], Pf, Oc[1][nb]);
      }
      __builtin_amdgcn_s_setprio(0);
    }
    // end barrier: all waves done reading buf -> next iter may overwrite buf^1
    asm volatile("s_waitcnt lgkmcnt(0)" ::: "memory");
    __builtin_amdgcn_s_barrier();
    __builtin_amdgcn_sched_barrier(0);
  }

  // final softmax denominators: reduce partial sums across quads
#pragma unroll
  for (int nt = 0; nt < 2; ++nt) {
    lsum[nt] += __shfl_xor(lsum[nt], 16, 64);
    lsum[nt] += __shfl_xor(lsum[nt], 32, 64);
  }
  if (lane < 16) { l_s[(w * 2) * 16 + l16] = lsum[0]; l_s[(w * 2 + 1) * 16 + l16] = lsum[1]; }
  __syncthreads();

  // epilogue: out[c][j] = O/l + LN1(query)[c][j]
  float linv[8];
#pragma unroll
  for (int nb = 0; nb < 8; ++nb) linv[nb] = 1.f / l_s[nb * 16 + l16];
#pragma unroll
  for (int mi = 0; mi < 2; ++mi) {
#pragma unroll
    for (int r = 0; r < 4; ++r) {
      int c = (w * 2 + mi) * 16 + quad * 4 + r;
      const float* qp = qb  + (size_t)c * SD + j0;
      const float* wp = l1w + (size_t)c * SD + j0;
      const float* bp = l1b + (size_t)c * SD + j0;
      float* op = out + (size_t)n * MEL + (size_t)c * SD + j0;
#pragma unroll
      for (int nb = 0; nb < 8; ++nb) {
        int j = nb * 16 + l16;
        float qn = (qp[j] * a_ln + b_ln) * wp[j] + bp[j];
        op[j] = Oc[mi][nb][r] * linv[nb] + qn;
      }
    }
  }
}

// ---------------- host launch ----------------
extern "C" void kernel_launch(void* const* d_in, const int* in_sizes, int n_in,
                              void* d_out, int out_size, void* d_ws, size_t ws_size,
                              hipStream_t stream)
{
  const float* q   = (const float*)d_in[0];
  const float* k   = (const float*)d_in[1];
  const float* v   = (const float*)d_in[2];
  const float* l1w = (const float*)d_in[3];
  const float* l1b = (const float*)d_in[4];
  const float* l2w = (const float*)d_in[5];
  const float* l2b = (const float*)d_in[6];
  const float* l3w = (const float*)d_in[7];
  const float* l3b = (const float*)d_in[8];
  const float* wq  = (const float*)d_in[9];
  const float* bq  = (const float*)d_in[10];
  const float* wk  = (const float*)d_in[11];
  const float* bk  = (const float*)d_in[12];
  const float* wv  = (const float*)d_in[13];
  const float* bv  = (const float*)d_in[14];

  char* ws = (char*)d_ws;
  float* sums = (float*)ws;                          // [1536] partials (6KB)
  unsigned short* kT = (unsigned short*)(ws + 8192); // [64][1024][128] bf16
  unsigned short* vN = kT + (size_t)NS * MEL;        // [64][128][1024] bf16

  stats_kernel<<<768, 512, 0, stream>>>(q, k, v, sums);
  proj_kernel<<<dim3(64, 2, 8), 512, 0, stream>>>(k, v, l2w, l2b, l3w, l3b,
      wk, bk, wv, bv, sums, kT, vN);
  attn_kernel<<<dim3(64, 8), 256, 0, stream>>>(q, l1w, l1b, wq, bq, kT, vN,
      sums, (float*)d_out);
}

// Round 11
// 248.172 us; speedup vs baseline: 1.0536x; 1.0032x over previous
//
#include <hip/hip_runtime.h>

// N=64, C=128, S=H*W=1024. f32 I/O; bf16 MFMA (16x16x32) internally.
// ws: 8KB stats (4 partials) + kT 16MB (bf16 [n][s][c]) + vN 16MB ([n][c][s]).
// R11: R10 base (passed, attn 68.0us) + final safe bundle:
//  - proj: launch_bounds(512,6) -> 3 blocks/CU co-resident (was 2)
//  - stats: 4 independent accumulator chains
//  - attn: lsum split into 2 partials per nt (shorter VALU dep chain)

#define NS 64
#define CD 128
#define SD 1024
#define MEL (CD*SD)
#define SCALE2 0.1275174464f   // (1/sqrt(128)) * log2(e)

typedef __attribute__((ext_vector_type(4))) float floatx4;
typedef __attribute__((ext_vector_type(8))) short short8;
typedef __attribute__((ext_vector_type(4))) short short4v;

typedef __attribute__((address_space(1))) const void global_cvoid;
typedef __attribute__((address_space(3))) void lds_void;

__device__ __forceinline__ void gl16(const void* g, void* l) {
  __builtin_amdgcn_global_load_lds((global_cvoid*)g, (lds_void*)l, 16, 0, 0);
}
__device__ __forceinline__ unsigned short f2bf(float f) {
  union { float f; unsigned int i; } v; v.f = f;
  unsigned int i = v.i;
  return (unsigned short)((i + 0x7fffu + ((i >> 16) & 1u)) >> 16);  // RNE
}
__device__ __forceinline__ unsigned int pkbf(float lo, float hi) {
  unsigned int r;
  asm("v_cvt_pk_bf16_f32 %0, %1, %2" : "=v"(r) : "v"(lo), "v"(hi));  // RNE pack
  return r;
}
__device__ __forceinline__ float fexp2(float x) {   // 2^x
  float r; asm("v_exp_f32 %0, %1" : "=v"(r) : "v"(x)); return r;
}
__device__ __forceinline__ short8 ld8_bf16(const float* __restrict__ p) {
  floatx4 a = *(const floatx4*)p;
  floatx4 b = *(const floatx4*)(p + 4);
  union { unsigned int u[4]; short8 s; } r;
  r.u[0] = pkbf(a[0], a[1]);
  r.u[1] = pkbf(a[2], a[3]);
  r.u[2] = pkbf(b[0], b[1]);
  r.u[3] = pkbf(b[2], b[3]);
  return r.s;
}
__device__ __forceinline__ floatx4 mfma16(short8 a, short8 b, floatx4 c) {
  return __builtin_amdgcn_mfma_f32_16x16x32_bf16(a, b, c, 0, 0, 0);
}

// ---------------- Kernel 1: per-(tensor,sample) sum / sumsq ----------------
// 768 blocks: 4 partials per (t,n) -> exactly 3 blocks/CU, balanced.
__global__ __launch_bounds__(512) void stats_kernel(
    const float* __restrict__ q, const float* __restrict__ k,
    const float* __restrict__ v, float* __restrict__ sums)
{
  int b = blockIdx.x;                 // 0..767
  int tn = b >> 2, part = b & 3;
  int t = tn >> 6;
  const float* x = (t == 0 ? q : (t == 1 ? k : v))
                 + (size_t)(tn & 63) * MEL + part * (MEL / 4);
  float sa = 0.f, sb2 = 0.f, sc = 0.f, sd = 0.f;    // 4 independent chains
  float qa = 0.f, qb2 = 0.f, qc = 0.f, qd = 0.f;
#pragma unroll
  for (int it = 0; it < 16; ++it) {
    floatx4 u = *(const floatx4*)(x + it * 2048 + threadIdx.x * 4);
    sa += u[0]; qa += u[0] * u[0];
    sb2 += u[1]; qb2 += u[1] * u[1];
    sc += u[2]; qc += u[2] * u[2];
    sd += u[3]; qd += u[3] * u[3];
  }
  float s1 = (sa + sb2) + (sc + sd);
  float s2 = (qa + qb2) + (qc + qd);
#pragma unroll
  for (int off = 32; off; off >>= 1) {
    s1 += __shfl_xor(s1, off, 64);
    s2 += __shfl_xor(s2, off, 64);
  }
  __shared__ float r1[8], r2[8];
  int w = threadIdx.x >> 6;
  if ((threadIdx.x & 63) == 0) { r1[w] = s1; r2[w] = s2; }
  __syncthreads();
  if (threadIdx.x == 0) {
    float a = 0.f, c = 0.f;
#pragma unroll
    for (int i = 0; i < 8; ++i) { a += r1[i]; c += r2[i]; }
    sums[part * 192 + tn] = a;
    sums[768 + part * 192 + tn] = c;
  }
}

__device__ __forceinline__ void ln_coeffs(const float* __restrict__ sums,
                                          int g, float& a_ln, float& b_ln)
{
  float s1 = ((sums[g] + sums[192 + g]) + (sums[384 + g] + sums[576 + g]));
  float s2 = ((sums[768 + g] + sums[960 + g]) + (sums[1152 + g] + sums[1344 + g]));
  float mu  = s1 * (1.f / MEL);
  float var = s2 * (1.f / MEL) - mu * mu;
  float rs  = rsqrtf(var + 1e-5f);
  a_ln = rs; b_ln = -mu * rs;
}

// ---------------- Kernel 2: fused LN + 1x1-conv for K and V ----------------
// launch_bounds(512,6): 3 blocks/CU co-resident (VGPR cap 85).
__global__ __launch_bounds__(512, 6) void proj_kernel(
  const float* __restrict__ k, const float* __restrict__ v,
  const float* __restrict__ l2w, const float* __restrict__ l2b,
  const float* __restrict__ l3w, const float* __restrict__ l3b,
  const float* __restrict__ wk, const float* __restrict__ bk,
  const float* __restrict__ wv, const float* __restrict__ bv,
  const float* __restrict__ sums,
  unsigned short* __restrict__ kT, unsigned short* __restrict__ vN)
{
  int n  = blockIdx.x, t = blockIdx.y, st = blockIdx.z;
  const float* x  = (t == 0 ? k : v) + (size_t)n * MEL;
  const float* lw = (t == 0 ? l2w : l3w);
  const float* lb = (t == 0 ? l2b : l3b);
  const float* W  = (t == 0 ? wk : wv);
  const float* Bs = (t == 0 ? bk : bv);

  float a_ln, b_ln;
  ln_coeffs(sums, (t + 1) * 64 + n, a_ln, b_ln);

  __shared__ __align__(16) unsigned short Xt[128 * 136];  // [s][c], stride 136

  int tid = threadIdx.x;
  int cb = tid & 15, sb = (tid >> 4) & 15, half = tid >> 8;
  int s0 = st * 128;

  unsigned int w32[8][2];
#pragma unroll
  for (int pr = 0; pr < 2; ++pr) {
    int c0 = cb * 8 + half * 4 + pr * 2;
    const float* xp0 = x  + (size_t)c0 * SD + s0 + sb * 8;
    const float* wp0 = lw + (size_t)c0 * SD + s0 + sb * 8;
    const float* bp0 = lb + (size_t)c0 * SD + s0 + sb * 8;
    float xv0[8], xv1[8], wv0[8], wv1[8], bv0[8], bv1[8];
    *(floatx4*)xv0 = *(const floatx4*)xp0;       *(floatx4*)(xv0+4) = *(const floatx4*)(xp0+4);
    *(floatx4*)xv1 = *(const floatx4*)(xp0+SD);  *(floatx4*)(xv1+4) = *(const floatx4*)(xp0+SD+4);
    *(floatx4*)wv0 = *(const floatx4*)wp0;       *(floatx4*)(wv0+4) = *(const floatx4*)(wp0+4);
    *(floatx4*)wv1 = *(const floatx4*)(wp0+SD);  *(floatx4*)(wv1+4) = *(const floatx4*)(wp0+SD+4);
    *(floatx4*)bv0 = *(const floatx4*)bp0;       *(floatx4*)(bv0+4) = *(const floatx4*)(bp0+4);
    *(floatx4*)bv1 = *(const floatx4*)(bp0+SD);  *(floatx4*)(bv1+4) = *(const floatx4*)(bp0+SD+4);
#pragma unroll
    for (int js = 0; js < 8; ++js) {
      float lo = (xv0[js] * a_ln + b_ln) * wv0[js] + bv0[js];
      float hi = (xv1[js] * a_ln + b_ln) * wv1[js] + bv1[js];
      w32[js][pr] = pkbf(lo, hi);
    }
  }
#pragma unroll
  for (int js = 0; js < 8; ++js) {
    unsigned int* d = (unsigned int*)&Xt[(sb * 8 + js) * 136 + cb * 8 + half * 4];
    d[0] = w32[js][0]; d[1] = w32[js][1];
  }
  __syncthreads();

  int lane = tid & 63, w = tid >> 6;
  int quad = lane >> 4, l16 = lane & 15;

  short8 Af[4];
#pragma unroll
  for (int kk = 0; kk < 4; ++kk)
    Af[kk] = ld8_bf16(W + (w * 16 + l16) * CD + kk * 32 + quad * 8);

  floatx4 acc[8];
  floatx4 zz = {0.f, 0.f, 0.f, 0.f};
#pragma unroll
  for (int nb = 0; nb < 8; ++nb) acc[nb] = zz;
#pragma unroll
  for (int kk = 0; kk < 4; ++kk)
#pragma unroll
    for (int nb = 0; nb < 8; ++nb) {
      short8 Bf = *(const short8*)&Xt[(nb * 16 + l16) * 136 + kk * 32 + quad * 8];
      acc[nb] = mfma16(Af[kk], Bf, acc[nb]);
    }

  float bsv[4];
#pragma unroll
  for (int r = 0; r < 4; ++r) bsv[r] = Bs[w * 16 + quad * 4 + r];

  __syncthreads();
  unsigned short* Ot = Xt;             // 128 x 130 ushort
#pragma unroll
  for (int nb = 0; nb < 8; ++nb) {
    if (t == 0) {
      unsigned int* d = (unsigned int*)&Ot[(nb * 16 + l16) * 130 + w * 16 + quad * 4];
      d[0] = pkbf(acc[nb][0] + bsv[0], acc[nb][1] + bsv[1]);
      d[1] = pkbf(acc[nb][2] + bsv[2], acc[nb][3] + bsv[3]);
    } else {
      int sl = nb * 16 + l16;
#pragma unroll
      for (int r = 0; r < 4; ++r)
        Ot[(w * 16 + quad * 4 + r) * 130 + sl] = f2bf(acc[nb][r] + bsv[r]);
    }
  }
  __syncthreads();
  unsigned short* gbase = (t == 0) ? (kT + (size_t)n * MEL + (size_t)s0 * CD)
                                   : (vN + (size_t)n * MEL + s0);
#pragma unroll
  for (int p = 0; p < 4; ++p) {
    int g = p * 512 + tid;
    int row = g >> 4, chunk = g & 15;
    short8 val = *(const short8*)&Ot[row * 130 + chunk * 8];
    if (t == 0)
      *(short8*)(gbase + (size_t)row * CD + chunk * 8) = val;
    else
      *(short8*)(gbase + (size_t)row * SD + chunk * 8) = val;
  }
}

// ------- Kernel 3: fused q-proj + flash attention (no-max softmax) -------
// R10 structure (passed, 68.0us): LDS 81920B, KV double-buffer, counted
// vmcnt(8), lgkmcnt-only barriers mid-tile, tile-0 staged under phase A.
__device__ __forceinline__ void stage_tile(
    const unsigned short* __restrict__ kbase0,
    const unsigned short* __restrict__ vbase0,
    char* smem, int ti, int buf, int w, int lane)
{
  const unsigned short* kb = kbase0 + (size_t)ti * 64 * CD;
  char* KD = smem + buf * 32768;
  char* VD = smem + buf * 32768 + 16384;
#pragma unroll
  for (int it = 0; it < 4; ++it) {   // Ks[i][c], chunk-xor by (i&7)
    int nch = w * 256 + it * 64 + lane;
    int i = nch >> 4, cc = nch & 15;
    int csrc = (cc & 8) | ((cc & 7) ^ (i & 7));
    gl16(kb + i * CD + csrc * 8, KD + (w * 256 + it * 64) * 16);
  }
#pragma unroll
  for (int it = 0; it < 4; ++it) {   // Vs[c][i], chunk-xor by (c&7)
    int nch = w * 256 + it * 64 + lane;
    int c = nch >> 3, ci = nch & 7;
    int isrc = ci ^ (c & 7);
    gl16(vbase0 + (size_t)c * SD + ti * 64 + isrc * 8, VD + (w * 256 + it * 64) * 16);
  }
}

__global__ __launch_bounds__(256, 2) void attn_kernel(
  const float* __restrict__ qraw, const float* __restrict__ l1w,
  const float* __restrict__ l1b, const float* __restrict__ wq,
  const float* __restrict__ bq,
  const unsigned short* __restrict__ kT, const unsigned short* __restrict__ vN,
  const float* __restrict__ sums, float* __restrict__ out)
{
  int n = blockIdx.x, jt = blockIdx.y;
  int j0 = jt * 128;

  __shared__ __align__(16) char smem[81920];
  unsigned short* Xt = (unsigned short*)(smem + 32768);
  unsigned short* Ps = (unsigned short*)(smem + 65536);        // 16KB
  float* l_s = (float*)smem;                                   // epilogue alias

  int tid = threadIdx.x, lane = tid & 63, w = tid >> 6;
  int quad = lane >> 4, l16 = lane & 15;

  const unsigned short* kbase0 = kT + (size_t)n * MEL;
  const unsigned short* vbase0 = vN + (size_t)n * MEL;

  // prefetch tile 0 into Ks0/Vs0 [0,32K) -- latency hidden under phase A
  stage_tile(kbase0, vbase0, smem, 0, 0, w, lane);

  float a_ln, b_ln;
  ln_coeffs(sums, n, a_ln, b_ln);
  const float* qb = qraw + (size_t)n * MEL;

  // --- Phase A: LN1(q) -> Xt[j][c] via 8x8 register-transpose blocks ---
  {
    int cb = tid & 15, sb = tid >> 4;       // 16 x 16
    unsigned int w32[8][4];
#pragma unroll
    for (int pr = 0; pr < 4; ++pr) {
      int c0 = cb * 8 + pr * 2;
      const float* xp0 = qb  + (size_t)c0 * SD + j0 + sb * 8;
      const float* wp0 = l1w + (size_t)c0 * SD + j0 + sb * 8;
      const float* bp0 = l1b + (size_t)c0 * SD + j0 + sb * 8;
      float xv0[8], xv1[8], wv0[8], wv1[8], bv0[8], bv1[8];
      *(floatx4*)xv0 = *(const floatx4*)xp0;       *(floatx4*)(xv0+4) = *(const floatx4*)(xp0+4);
      *(floatx4*)xv1 = *(const floatx4*)(xp0+SD);  *(floatx4*)(xv1+4) = *(const floatx4*)(xp0+SD+4);
      *(floatx4*)wv0 = *(const floatx4*)wp0;       *(floatx4*)(wv0+4) = *(const floatx4*)(wp0+4);
      *(floatx4*)wv1 = *(const floatx4*)(wp0+SD);  *(floatx4*)(wv1+4) = *(const floatx4*)(wp0+SD+4);
      *(floatx4*)bv0 = *(const floatx4*)bp0;       *(floatx4*)(bv0+4) = *(const floatx4*)(bp0+4);
      *(floatx4*)bv1 = *(const floatx4*)(bp0+SD);  *(floatx4*)(bv1+4) = *(const floatx4*)(bp0+SD+4);
#pragma unroll
      for (int js = 0; js < 8; ++js) {
        float lo = (xv0[js] * a_ln + b_ln) * wv0[js] + bv0[js];
        float hi = (xv1[js] * a_ln + b_ln) * wv1[js] + bv1[js];
        w32[js][pr] = pkbf(lo, hi);
      }
    }
#pragma unroll
    for (int js = 0; js < 8; ++js)
      *(floatx4*)&Xt[(sb * 8 + js) * 136 + cb * 8] = *(floatx4*)w32[js];
  }
  __syncthreads();

  // q-projection: C[c_out][j] = wq . Xt
  floatx4 zz = {0.f, 0.f, 0.f, 0.f};
  {
    short8 Af[2][4];
#pragma unroll
    for (int mi = 0; mi < 2; ++mi)
#pragma unroll
      for (int kk = 0; kk < 4; ++kk)
        Af[mi][kk] = ld8_bf16(wq + ((w * 2 + mi) * 16 + l16) * CD + kk * 32 + quad * 8);
    floatx4 accq[2][8];
#pragma unroll
    for (int mi = 0; mi < 2; ++mi)
#pragma unroll
      for (int nb = 0; nb < 8; ++nb) accq[mi][nb] = zz;
#pragma unroll
    for (int kk = 0; kk < 4; ++kk)
#pragma unroll
      for (int nb = 0; nb < 8; ++nb) {
        short8 Bf = *(const short8*)&Xt[(nb * 16 + l16) * 136 + kk * 32 + quad * 8];
        accq[0][nb] = mfma16(Af[0][kk], Bf, accq[0][nb]);
        accq[1][nb] = mfma16(Af[1][kk], Bf, accq[1][nb]);
      }
    __syncthreads();
    float bqs[2][4];
#pragma unroll
    for (int mi = 0; mi < 2; ++mi)
#pragma unroll
      for (int r = 0; r < 4; ++r) bqs[mi][r] = bq[(w * 2 + mi) * 16 + quad * 4 + r];
#pragma unroll
    for (int mi = 0; mi < 2; ++mi)
#pragma unroll
      for (int nb = 0; nb < 8; ++nb) {
        unsigned int* d = (unsigned int*)&Xt[(nb * 16 + l16) * 136 + (w * 2 + mi) * 16 + quad * 4];
        d[0] = pkbf(accq[mi][nb][0] + bqs[mi][0], accq[mi][nb][1] + bqs[mi][1]);
        d[1] = pkbf(accq[mi][nb][2] + bqs[mi][2], accq[mi][nb][3] + bqs[mi][3]);
      }
  }
  __syncthreads();

  short8 Qf[2][4];    // B-frags: n = j = (w*2+nt)*16 + l16
#pragma unroll
  for (int nt = 0; nt < 2; ++nt)
#pragma unroll
    for (int kk = 0; kk < 4; ++kk)
      Qf[nt][kk] = *(const short8*)&Xt[((w * 2 + nt) * 16 + l16) * 136 + kk * 32 + quad * 8];
  __syncthreads();   // Xt dead: Ks1/Vs1 region free for staging from iter 0

  floatx4 Oc[2][8];
#pragma unroll
  for (int mi = 0; mi < 2; ++mi)
#pragma unroll
    for (int nb = 0; nb < 8; ++nb) Oc[mi][nb] = zz;
  float lsA[2] = {0.f, 0.f}, lsB[2] = {0.f, 0.f};   // 2 chains per nt

  for (int itile = 0; itile < 16; ++itile) {
    int buf = itile & 1;
    if (itile < 15) {
      stage_tile(kbase0, vbase0, smem, itile + 1, buf ^ 1, w, lane);
      asm volatile("s_waitcnt vmcnt(8)" ::: "memory");  // stage(itile) landed
    } else {
      asm volatile("s_waitcnt vmcnt(0)" ::: "memory");
    }
    __builtin_amdgcn_s_barrier();          // all waves' stage(itile) landed
    __builtin_amdgcn_sched_barrier(0);

    const unsigned short* Ks = (const unsigned short*)(smem + buf * 32768);
    const unsigned short* Vs = (const unsigned short*)(smem + buf * 32768 + 16384);

    // QK: S[i][j], A = K (m=i), B = Q (n=j)
    floatx4 Sa[4][2];
#pragma unroll
    for (int mt = 0; mt < 4; ++mt) { Sa[mt][0] = zz; Sa[mt][1] = zz; }
    __builtin_amdgcn_s_setprio(1);
#pragma unroll
    for (int kk = 0; kk < 4; ++kk)
#pragma unroll
      for (int mt = 0; mt < 4; ++mt) {
        short8 Kf = *(const short8*)&Ks[(mt * 16 + l16) * 128 + (((kk * 4 + quad) ^ (l16 & 7)) * 8)];
        Sa[mt][0] = mfma16(Kf, Qf[0][kk], Sa[mt][0]);
        Sa[mt][1] = mfma16(Kf, Qf[1][kk], Sa[mt][1]);
      }
    __builtin_amdgcn_s_setprio(0);

    // no-max softmax: p = exp2(S*scale*log2e); accumulate l; Ps[j][i] writes
#pragma unroll
    for (int nt = 0; nt < 2; ++nt) {
      int jrow = (w * 2 + nt) * 16 + l16;
      int rowbase = jrow * 64;
      int sub = (quad & 1) * 4;
#pragma unroll
      for (int mt = 0; mt < 4; ++mt) {
        float p0 = fexp2(Sa[mt][nt][0] * SCALE2);
        float p1 = fexp2(Sa[mt][nt][1] * SCALE2);
        float p2 = fexp2(Sa[mt][nt][2] * SCALE2);
        float p3 = fexp2(Sa[mt][nt][3] * SCALE2);
        if (mt & 1) lsB[nt] += (p0 + p1) + (p2 + p3);
        else        lsA[nt] += (p0 + p1) + (p2 + p3);
        int ci = mt * 2 + (quad >> 1);
        int cis = ci ^ (l16 & 7);
        unsigned int* d = (unsigned int*)&Ps[rowbase + cis * 8 + sub];
        d[0] = pkbf(p0, p1);
        d[1] = pkbf(p2, p3);
      }
    }
    // Ps visibility barrier WITHOUT vmcnt drain (prefetch stays in flight)
    asm volatile("s_waitcnt lgkmcnt(0)" ::: "memory");
    __builtin_amdgcn_s_barrier();
    __builtin_amdgcn_sched_barrier(0);

    // PV: O[c][j] += V . P   (A = V m=c, B = P n=j)
#pragma unroll
    for (int kk = 0; kk < 2; ++kk) {
      short8 Vf[2];
#pragma unroll
      for (int mi = 0; mi < 2; ++mi) {
        int c = (w * 2 + mi) * 16 + l16;
        Vf[mi] = *(const short8*)&Vs[c * 64 + (((kk * 4 + quad) ^ (l16 & 7)) * 8)];
      }
      __builtin_amdgcn_s_setprio(1);
#pragma unroll
      for (int nb = 0; nb < 8; ++nb) {
        short8 Pf = *(const short8*)&Ps[(nb * 16 + l16) * 64 + (((kk * 4 + quad) ^ (l16 & 7)) * 8)];
        Oc[0][nb] = mfma16(Vf[0], Pf, Oc[0][nb]);
        Oc[1][nb] = mfma16(Vf[1], Pf, Oc[1][nb]);
      }
      __builtin_amdgcn_s_setprio(0);
    }
    // end barrier: all waves done reading buf -> next iter may overwrite buf^1
    asm volatile("s_waitcnt lgkmcnt(0)" ::: "memory");
    __builtin_amdgcn_s_barrier();
    __builtin_amdgcn_sched_barrier(0);
  }

  // final softmax denominators: reduce partial sums across quads
  float lsum[2];
#pragma unroll
  for (int nt = 0; nt < 2; ++nt) {
    lsum[nt] = lsA[nt] + lsB[nt];
    lsum[nt] += __shfl_xor(lsum[nt], 16, 64);
    lsum[nt] += __shfl_xor(lsum[nt], 32, 64);
  }
  if (lane < 16) { l_s[(w * 2) * 16 + l16] = lsum[0]; l_s[(w * 2 + 1) * 16 + l16] = lsum[1]; }
  __syncthreads();

  // epilogue: out[c][j] = O/l + LN1(query)[c][j]
  float linv[8];
#pragma unroll
  for (int nb = 0; nb < 8; ++nb) linv[nb] = 1.f / l_s[nb * 16 + l16];
#pragma unroll
  for (int mi = 0; mi < 2; ++mi) {
#pragma unroll
    for (int r = 0; r < 4; ++r) {
      int c = (w * 2 + mi) * 16 + quad * 4 + r;
      const float* qp = qb  + (size_t)c * SD + j0;
      const float* wp = l1w + (size_t)c * SD + j0;
      const float* bp = l1b + (size_t)c * SD + j0;
      float* op = out + (size_t)n * MEL + (size_t)c * SD + j0;
#pragma unroll
      for (int nb = 0; nb < 8; ++nb) {
        int j = nb * 16 + l16;
        float qn = (qp[j] * a_ln + b_ln) * wp[j] + bp[j];
        op[j] = Oc[mi][nb][r] * linv[nb] + qn;
      }
    }
  }
}

// ---------------- host launch ----------------
extern "C" void kernel_launch(void* const* d_in, const int* in_sizes, int n_in,
                              void* d_out, int out_size, void* d_ws, size_t ws_size,
                              hipStream_t stream)
{
  const float* q   = (const float*)d_in[0];
  const float* k   = (const float*)d_in[1];
  const float* v   = (const float*)d_in[2];
  const float* l1w = (const float*)d_in[3];
  const float* l1b = (const float*)d_in[4];
  const float* l2w = (const float*)d_in[5];
  const float* l2b = (const float*)d_in[6];
  const float* l3w = (const float*)d_in[7];
  const float* l3b = (const float*)d_in[8];
  const float* wq  = (const float*)d_in[9];
  const float* bq  = (const float*)d_in[10];
  const float* wk  = (const float*)d_in[11];
  const float* bk  = (const float*)d_in[12];
  const float* wv  = (const float*)d_in[13];
  const float* bv  = (const float*)d_in[14];

  char* ws = (char*)d_ws;
  float* sums = (float*)ws;                          // [1536] partials (6KB)
  unsigned short* kT = (unsigned short*)(ws + 8192); // [64][1024][128] bf16
  unsigned short* vN = kT + (size_t)NS * MEL;        // [64][128][1024] bf16

  stats_kernel<<<768, 512, 0, stream>>>(q, k, v, sums);
  proj_kernel<<<dim3(64, 2, 8), 512, 0, stream>>>(k, v, l2w, l2b, l3w, l3b,
      wk, bk, wv, bv, sums, kT, vN);
  attn_kernel<<<dim3(64, 8), 256, 0, stream>>>(q, l1w, l1b, wq, bq, kT, vN,
      sums, (float*)d_out);
}